// Round 5
// baseline (917.110 us; speedup 1.0000x reference)
//
#include <hip/hip_runtime.h>
#include <hip/hip_bf16.h>
#include <math.h>

// Problem constants
#define NN 50000
#define PP 200000
#define LL 6
#define DD 128      // IN_DIM == OUT_DIM
#define HH 4        // heads

// Tiling
#define TM 64       // paths per workgroup
#define NT 512      // threads per workgroup (8 waves)
#define HPAD 132    // fp32 row stride for final-h LDS (bank spread)

typedef __attribute__((ext_vector_type(8))) short short8;   // 8 bf16 (MFMA A/B frag)
typedef __attribute__((ext_vector_type(4))) float f32x4;    // MFMA C/D frag

struct f3 { float x, y, z; };   // 12B packed, 4B-aligned (dwordx3)

__device__ __forceinline__ unsigned short f2bf(float v) {
    __hip_bfloat16 h = __float2bfloat16(v);
    return *(unsigned short*)&h;
}
__device__ __forceinline__ float bf2f(unsigned short u) {
    union { unsigned int i; float f; } c; c.i = ((unsigned int)u) << 16; return c.f;
}
__device__ __forceinline__ float fast_rcp(float x) { return __builtin_amdgcn_rcpf(x); }
__device__ __forceinline__ float fast_sigmoid(float x) {
    return fast_rcp(1.f + __expf(-x));
}
__device__ __forceinline__ float fast_tanh(float x) {
    float e = __expf(-2.f * fabsf(x));
    float t = (1.f - e) * fast_rcp(1.f + e);
    return copysignf(t, x);
}

// ---------------------------------------------------------------------------
// Prep: cast W_hh to bf16.
// ---------------------------------------------------------------------------
__global__ void prep_w_kernel(const float* __restrict__ w_hh,
                              unsigned short* __restrict__ whb) {
    int i = blockIdx.x * 256 + threadIdx.x;
    if (i < 3 * DD * DD) whb[i] = f2bf(w_hh[i]);
}

// ---------------------------------------------------------------------------
// Counting sort of paths by destination row (= path_list[p][5]).
// ---------------------------------------------------------------------------
__global__ void histo_kernel(const int* __restrict__ path_list,
                             int* __restrict__ cnt) {
    int p = blockIdx.x * 256 + threadIdx.x;
    if (p < PP) atomicAdd(&cnt[path_list[p * LL + (LL - 1)]], 1);
}

__global__ void scan_kernel(const int* __restrict__ cnt,
                            int* __restrict__ offs,
                            int* __restrict__ cursor) {
    __shared__ int ls[256];
    const int t = threadIdx.x;
    const int chunk = (NN + 255) / 256;
    int s = 0;
    for (int j = 0; j < chunk; ++j) {
        int i = t + j * 256;
        if (i < NN) s += cnt[i];
    }
    ls[t] = s; __syncthreads();
    for (int off = 1; off < 256; off <<= 1) {
        int v = (t >= off) ? ls[t - off] : 0;
        __syncthreads();
        ls[t] += v;
        __syncthreads();
    }
    int run = (t == 0) ? 0 : ls[t - 1];
    for (int j = 0; j < chunk; ++j) {
        int i = t + j * 256;
        if (i < NN) { offs[i] = run; cursor[i] = run; run += cnt[i]; }
    }
}

__global__ void scatter_kernel(const int* __restrict__ path_list,
                               int* __restrict__ cursor,
                               int* __restrict__ sorted) {
    int p = blockIdx.x * 256 + threadIdx.x;
    if (p < PP) {
        int row = path_list[p * LL + (LL - 1)];
        int k = atomicAdd(&cursor[row], 1);
        sorted[k] = p;
    }
}

// ---------------------------------------------------------------------------
// gi GEMM: gi[node][d][c] = x[node] @ W_ih[c*128+d] + biases (fused).
// Layout [node][128][3] fp32 packed -> GRU reads all 3 gates of (node,d)
// with ONE dwordx3 load.
// ---------------------------------------------------------------------------
__global__ __launch_bounds__(512, 2)
void gi_gemm_kernel(const float* __restrict__ x,     // [N][128]
                    const float* __restrict__ w_ih,  // [384][128]
                    const float* __restrict__ b_ih,
                    const float* __restrict__ b_hh,
                    float* __restrict__ gi)          // [N][128][3]
{
    const int tid  = threadIdx.x;
    const int lane = tid & 63;
    const int wave = tid >> 6;
    const int lcol = lane & 15;
    const int quad = lane >> 4;
    const int ko   = quad * 8;
    const int d    = wave * 16 + lcol;
    const int r0   = blockIdx.x * 64;

    short8 B[3][4];
    float bias[3];
    #pragma unroll
    for (int c = 0; c < 3; ++c) {
        int col = c * 128 + d;
        #pragma unroll
        for (int ks = 0; ks < 4; ++ks) {
            const float4* src = (const float4*)(w_ih + (size_t)col * 128 + ks * 32 + ko);
            float4 f0 = src[0], f1 = src[1];
            short8 b;
            b[0] = (short)f2bf(f0.x); b[1] = (short)f2bf(f0.y);
            b[2] = (short)f2bf(f0.z); b[3] = (short)f2bf(f0.w);
            b[4] = (short)f2bf(f1.x); b[5] = (short)f2bf(f1.y);
            b[6] = (short)f2bf(f1.z); b[7] = (short)f2bf(f1.w);
            B[c][ks] = b;
        }
        bias[c] = b_ih[col] + ((c < 2) ? b_hh[col] : 0.f);
    }

    f32x4 acc[3][4];
    #pragma unroll
    for (int c = 0; c < 3; ++c)
        #pragma unroll
        for (int rt = 0; rt < 4; ++rt)
            acc[c][rt] = (f32x4){bias[c], bias[c], bias[c], bias[c]};

    #pragma unroll
    for (int ks = 0; ks < 4; ++ks) {
        #pragma unroll
        for (int rt = 0; rt < 4; ++rt) {
            int row = r0 + rt * 16 + lcol;
            if (row >= NN) row = NN - 1;          // clamp loads, stores guarded
            const float4* src = (const float4*)(x + (size_t)row * 128 + ks * 32 + ko);
            float4 f0 = src[0], f1 = src[1];
            short8 av;
            av[0] = (short)f2bf(f0.x); av[1] = (short)f2bf(f0.y);
            av[2] = (short)f2bf(f0.z); av[3] = (short)f2bf(f0.w);
            av[4] = (short)f2bf(f1.x); av[5] = (short)f2bf(f1.y);
            av[6] = (short)f2bf(f1.z); av[7] = (short)f2bf(f1.w);
            acc[0][rt] = __builtin_amdgcn_mfma_f32_16x16x32_bf16(av, B[0][ks], acc[0][rt], 0, 0, 0);
            acc[1][rt] = __builtin_amdgcn_mfma_f32_16x16x32_bf16(av, B[1][ks], acc[1][rt], 0, 0, 0);
            acc[2][rt] = __builtin_amdgcn_mfma_f32_16x16x32_bf16(av, B[2][ks], acc[2][rt], 0, 0, 0);
        }
    }

    #pragma unroll
    for (int rt = 0; rt < 4; ++rt)
        #pragma unroll
        for (int rr = 0; rr < 4; ++rr) {
            int row = r0 + rt * 16 + quad * 4 + rr;
            if (row < NN) {
                float* o = gi + (size_t)row * 384 + d * 3;
                o[0] = acc[0][rt][rr];
                o[1] = acc[1][rt][rr];
                o[2] = acc[2][rt][rr];
            }
        }
}

// ---------------------------------------------------------------------------
// Pass A: h-side-only MFMA GRU at the proven no-spill point (512,2)/TM=64,
// with in-loop latency surgically removed:
//  - gi packed [node][128][3]: 16 dwordx3 gathers/thread/step (vs 48 scalar).
//  - gather software-pipelined one step ahead: g[] consumed at acc-init of
//    step t, immediately re-issued for t+1 -> ~900cy HBM latency spans
//    MFMA+epilogue+barrier instead of sitting in front of the MFMAs.
//  - raw s_barrier with lgkmcnt(0) ONLY (no vmcnt drain): prefetched global
//    loads stay in flight across the step boundary (m194-m199 pattern).
//    LDS h-exchange correctness needs only lgkm drain + barrier.
//  - hs double-buffered, ONE barrier per step. t-loop not unrolled.
// ---------------------------------------------------------------------------
__global__ __launch_bounds__(NT, 2)
void gru_att_kernel(const float* __restrict__ gi,             // [N][128][3] fp32
                    const int*   __restrict__ path_list,
                    const unsigned short* __restrict__ whb,   // [384][128] bf16
                    const float* __restrict__ b_hh,
                    const float* __restrict__ a,              // [128][4]
                    float* __restrict__ att_sum,              // [N][4]
                    unsigned short* __restrict__ emb,         // [P][128] bf16
                    float* __restrict__ att_un_g)             // [P][4]
{
    // smem: [0,16384) hs0 | [16384,32768) hs1 | hs_f fp32 aliases [0,33792)
    //       [33792,41984) red_s [64][8][4] | [41984,43520) nodes_s [TM*LL]
    __shared__ __align__(16) unsigned char smem[43520];
    unsigned short* hs0    = (unsigned short*)smem;
    unsigned short* hs1    = (unsigned short*)(smem + 16384);
    float*          hs_f   = (float*)smem;                 // alias (final step only)
    float*          red_s  = (float*)(smem + 33792);       // [64][8][4]
    int*            nodes_s= (int*)(smem + 41984);         // [TM*LL]

    const int tid  = threadIdx.x;
    const int lane = tid & 63;
    const int wave = tid >> 6;
    const int lcol = lane & 15;
    const int quad = lane >> 4;
    const int d    = wave * 16 + lcol;
    const int p0   = blockIdx.x * TM;
    const int ko   = quad * 8;

    // persistent h-side B fragments (c=0:r, 1:z, 2:n) — 48 VGPRs
    short8 Bh[3][4];
    #pragma unroll
    for (int c = 0; c < 3; ++c)
        #pragma unroll
        for (int ks = 0; ks < 4; ++ks)
            Bh[c][ks] = *(const short8*)(whb + (size_t)(c * DD + d) * DD + ks * 32 + ko);
    const float bhn = b_hh[d + 256];

    for (int i = tid; i < TM * LL; i += NT) nodes_s[i] = path_list[(size_t)p0 * LL + i];
    for (int i = tid; i < TM * DD / 8; i += NT)
        ((uint4*)hs0)[i] = make_uint4(0u, 0u, 0u, 0u);

    float hreg[16];
    #pragma unroll
    for (int i = 0; i < 16; ++i) hreg[i] = 0.f;

    __syncthreads();   // nodes_s + hs0 zero visible

    // prefetch gi for t=0
    f3 g[16];
    #pragma unroll
    for (int rt = 0; rt < 4; ++rt)
        #pragma unroll
        for (int r = 0; r < 4; ++r) {
            const int p = rt * 16 + quad * 4 + r;
            const int node = nodes_s[p * LL + 0];
            g[rt * 4 + r] = *(const f3*)(gi + (size_t)node * 384 + d * 3);
        }

    #pragma unroll 1
    for (int t = 0; t < LL; ++t) {
        unsigned short* hr = (t & 1) ? hs1 : hs0;   // read buffer
        unsigned short* hw = (t & 1) ? hs0 : hs1;   // write buffer

        // Consume prefetched gi -> accumulator init (vmcnt wait lands here,
        // ~2k cycles after issue -> near-zero stall).
        float gin[16];
        f32x4 accR[4], accZ[4], accH[4];
        #pragma unroll
        for (int rt = 0; rt < 4; ++rt) {
            #pragma unroll
            for (int r = 0; r < 4; ++r) {
                const int idx = rt * 4 + r;
                accR[rt][r] = g[idx].x;     // ir + b_ih_r + b_hh_r
                accZ[rt][r] = g[idx].y;     // iz + b_ih_z + b_hh_z
                gin[idx]    = g[idx].z;     // in + b_ih_n
            }
            accH[rt] = (f32x4){bhn, bhn, bhn, bhn};
        }

        // Re-issue gather for t+1 into the same registers (WAR after consume)
        if (t < LL - 1) {
            #pragma unroll
            for (int rt = 0; rt < 4; ++rt)
                #pragma unroll
                for (int r = 0; r < 4; ++r) {
                    const int p = rt * 16 + quad * 4 + r;
                    const int node = nodes_s[p * LL + t + 1];
                    g[rt * 4 + r] = *(const f3*)(gi + (size_t)node * 384 + d * 3);
                }
        }

        // MFMA: h-side only (48 MFMAs, 16 ds_read_b128 per wave)
        #pragma unroll
        for (int ks = 0; ks < 4; ++ks) {
            const int kb = ks * 4 + quad;
            #pragma unroll
            for (int rt = 0; rt < 4; ++rt) {
                const int p = rt * 16 + lcol;
                short8 ah = *(const short8*)(hr + p * DD + ((kb ^ lcol) * 8));
                accR[rt] = __builtin_amdgcn_mfma_f32_16x16x32_bf16(ah, Bh[0][ks], accR[rt], 0, 0, 0);
                accZ[rt] = __builtin_amdgcn_mfma_f32_16x16x32_bf16(ah, Bh[1][ks], accZ[rt], 0, 0, 0);
                accH[rt] = __builtin_amdgcn_mfma_f32_16x16x32_bf16(ah, Bh[2][ks], accH[rt], 0, 0, 0);
            }
        }

        if (t == LL - 1) {
            // hs_f aliases hs0/hs1: all waves' ds_reads must complete first.
            asm volatile("s_waitcnt lgkmcnt(0)" ::: "memory");
            __builtin_amdgcn_s_barrier();
        }

        // GRU cell epilogue
        #pragma unroll
        for (int rt = 0; rt < 4; ++rt) {
            #pragma unroll
            for (int r = 0; r < 4; ++r) {
                const int idx = rt * 4 + r;
                const int p   = rt * 16 + quad * 4 + r;
                float rg = fast_sigmoid(accR[rt][r]);
                float zg = fast_sigmoid(accZ[rt][r]);
                float ng = fast_tanh(gin[idx] + rg * accH[rt][r]);  // accH = hn + b_hh_n
                float hnew = fmaf(zg, hreg[idx] - ng, ng);
                hreg[idx] = hnew;
                if (t < LL - 1) {
                    hw[p * DD + (((d >> 3) ^ (p & 15)) * 8) + (d & 7)] = f2bf(hnew);
                } else {
                    hs_f[p * HPAD + d] = hnew;   // fp32, aliases dead hs buffers
                }
            }
        }
        // End-of-step barrier: LDS drain only — prefetched global loads
        // stay in flight (NO vmcnt(0)).
        asm volatile("s_waitcnt lgkmcnt(0)" ::: "memory");
        __builtin_amdgcn_s_barrier();
    }

    __syncthreads();   // hs_f visible to the re-partitioned attention block

    // attention logits + emit bf16 path embedding
    // pi = tid>>3 (path 0..63), tt = tid&7 (8 threads/row, 16 d each)
    {
        int pi = tid >> 3, tt = tid & 7;
        float s0 = 0.f, s1 = 0.f, s2 = 0.f, s3 = 0.f;
        unsigned short pack[16];
        #pragma unroll
        for (int j = 0; j < 16; ++j) {
            int dd2 = tt * 16 + j;
            float hv = hs_f[pi * HPAD + dd2];
            pack[j] = f2bf(hv);
            float4 av = *(const float4*)(a + dd2 * 4);
            s0 += hv * av.x; s1 += hv * av.y; s2 += hv * av.z; s3 += hv * av.w;
        }
        uint4* dst = (uint4*)(emb + (size_t)(p0 + pi) * DD + tt * 16);
        dst[0] = *(uint4*)&pack[0];
        dst[1] = *(uint4*)&pack[8];
        float* rp = red_s + (pi * 8 + tt) * 4;
        rp[0] = s0; rp[1] = s1; rp[2] = s2; rp[3] = s3;
    }
    __syncthreads();
    if (tid < TM) {
        int pi = tid;
        int row = nodes_s[pi * LL + (LL - 1)];
        float4 e4;
        #pragma unroll
        for (int h = 0; h < HH; ++h) {
            float s = 0.f;
            #pragma unroll
            for (int tt = 0; tt < 8; ++tt) s += red_s[(pi * 8 + tt) * 4 + h];
            float lv = (s > 0.f) ? s : 0.2f * s;
            float e  = __expf(lv);
            ((float*)&e4)[h] = e;
            atomicAdd(&att_sum[row * HH + h], e);
        }
        *(float4*)(att_un_g + (size_t)(p0 + pi) * HH) = e4;
    }
}

// ---------------------------------------------------------------------------
// Pass B: per-node aggregation over its sorted paths. Atomic-free.
// ---------------------------------------------------------------------------
__global__ __launch_bounds__(256)
void agg_kernel(const unsigned short* __restrict__ emb,   // [P][128] bf16
                const float* __restrict__ att_un,         // [P][4]
                const float* __restrict__ att_sum,        // [N][4]
                const int* __restrict__ offs,
                const int* __restrict__ cnt,
                const int* __restrict__ sorted,
                float* __restrict__ out)                  // [N][512]
{
    int node = blockIdx.x * 2 + (threadIdx.x >> 7);
    int d    = threadIdx.x & 127;
    if (node >= NN) return;
    int start = offs[node];
    int len   = cnt[node];
    float a0 = 0.f, a1 = 0.f, a2 = 0.f, a3 = 0.f;
    for (int i = 0; i < len; ++i) {
        int p = sorted[start + i];
        float4 at = *(const float4*)(att_un + (size_t)p * 4);
        float ev = bf2f(emb[(size_t)p * DD + d]);
        a0 = fmaf(at.x, ev, a0);
        a1 = fmaf(at.y, ev, a1);
        a2 = fmaf(at.z, ev, a2);
        a3 = fmaf(at.w, ev, a3);
    }
    float4 s = *(const float4*)(att_sum + (size_t)node * 4);
    float* o = out + (size_t)node * 512 + d;
    o[0]   = (s.x > 0.f) ? a0 / s.x : 0.f;
    o[128] = (s.y > 0.f) ? a1 / s.y : 0.f;
    o[256] = (s.z > 0.f) ? a2 / s.z : 0.f;
    o[384] = (s.w > 0.f) ? a3 / s.w : 0.f;
}

extern "C" void kernel_launch(void* const* d_in, const int* in_sizes, int n_in,
                              void* d_out, int out_size, void* d_ws, size_t ws_size,
                              hipStream_t stream) {
    const float* x         = (const float*)d_in[0];
    const int*   path_list = (const int*)  d_in[1];
    const float* w_ih      = (const float*)d_in[2];
    const float* w_hh      = (const float*)d_in[3];
    const float* b_ih      = (const float*)d_in[4];
    const float* b_hh      = (const float*)d_in[5];
    const float* a         = (const float*)d_in[6];
    float* out = (float*)d_out;

    // workspace layout (all 16B-multiple sizes), total ~133.5 MB
    char* w = (char*)d_ws;
    float*          att_sum = (float*)w;                 w += 800000;       // N*4 f32
    int*            cnt     = (int*)w;                   w += 200000;       // N
    int*            offs    = (int*)w;                   w += 200000;       // N
    int*            cursor  = (int*)w;                   w += 200000;       // N
    int*            sorted  = (int*)w;                   w += 800000;       // P
    float*          att_un  = (float*)w;                 w += 3200000;      // P*4 f32
    float*          gi      = (float*)w;                 w += 76800000;     // N*128*3 f32
    unsigned short* whb     = (unsigned short*)w;        w += 98304;        // 384*128 bf16
    unsigned short* emb     = (unsigned short*)w;        w += 51200000;     // P*128 bf16

    hipMemsetAsync(att_sum, 0, 800000, stream);
    hipMemsetAsync(cnt, 0, 200000, stream);

    prep_w_kernel<<<(3 * DD * DD + 255) / 256, 256, 0, stream>>>(w_hh, whb);

    histo_kernel<<<(PP + 255) / 256, 256, 0, stream>>>(path_list, cnt);
    scan_kernel<<<1, 256, 0, stream>>>(cnt, offs, cursor);
    scatter_kernel<<<(PP + 255) / 256, 256, 0, stream>>>(path_list, cursor, sorted);

    gi_gemm_kernel<<<(NN + 63) / 64, 512, 0, stream>>>(x, w_ih, b_ih, b_hh, gi);

    gru_att_kernel<<<PP / TM, NT, 0, stream>>>(gi, path_list, whb,
                                               b_hh, a, att_sum, emb, att_un);

    agg_kernel<<<(NN + 1) / 2, 256, 0, stream>>>(emb, att_un, att_sum,
                                                 offs, cnt, sorted, out);
}

// Round 6
// 859.303 us; speedup vs baseline: 1.0673x; 1.0673x over previous
//
#include <hip/hip_runtime.h>
#include <hip/hip_bf16.h>
#include <math.h>

// Problem constants
#define NN 50000
#define PP 200000
#define LL 6
#define DD 128      // IN_DIM == OUT_DIM
#define HH 4        // heads

// Step-kernel tiling
#define TM 32       // paths per workgroup
#define NT 512      // threads per workgroup (8 waves, wave w owns cols 16w..16w+16)
#define HPAD 132    // fp32 row stride for final-h LDS (bank spread)

typedef __attribute__((ext_vector_type(8))) short short8;   // 8 bf16 (MFMA A/B frag)
typedef __attribute__((ext_vector_type(4))) float f32x4;    // MFMA C/D frag

struct f3 { float x, y, z; };   // 12B packed, 4B-aligned (dwordx3)

__device__ __forceinline__ unsigned short f2bf(float v) {
    __hip_bfloat16 h = __float2bfloat16(v);
    return *(unsigned short*)&h;
}
__device__ __forceinline__ float bf2f(unsigned short u) {
    union { unsigned int i; float f; } c; c.i = ((unsigned int)u) << 16; return c.f;
}
__device__ __forceinline__ float fast_rcp(float x) { return __builtin_amdgcn_rcpf(x); }
__device__ __forceinline__ float fast_sigmoid(float x) {
    return fast_rcp(1.f + __expf(-x));
}
__device__ __forceinline__ float fast_tanh(float x) {
    float e = __expf(-2.f * fabsf(x));
    float t = (1.f - e) * fast_rcp(1.f + e);
    return copysignf(t, x);
}

// ---------------------------------------------------------------------------
// Prep: cast W_hh to bf16.
// ---------------------------------------------------------------------------
__global__ void prep_w_kernel(const float* __restrict__ w_hh,
                              unsigned short* __restrict__ whb) {
    int i = blockIdx.x * 256 + threadIdx.x;
    if (i < 3 * DD * DD) whb[i] = f2bf(w_hh[i]);
}

// ---------------------------------------------------------------------------
// Counting sort of paths by destination row (= path_list[p][5]).
// ---------------------------------------------------------------------------
__global__ void histo_kernel(const int* __restrict__ path_list,
                             int* __restrict__ cnt) {
    int p = blockIdx.x * 256 + threadIdx.x;
    if (p < PP) atomicAdd(&cnt[path_list[p * LL + (LL - 1)]], 1);
}

__global__ void scan_kernel(const int* __restrict__ cnt,
                            int* __restrict__ offs,
                            int* __restrict__ cursor) {
    __shared__ int ls[256];
    const int t = threadIdx.x;
    const int chunk = (NN + 255) / 256;
    int s = 0;
    for (int j = 0; j < chunk; ++j) {
        int i = t + j * 256;
        if (i < NN) s += cnt[i];
    }
    ls[t] = s; __syncthreads();
    for (int off = 1; off < 256; off <<= 1) {
        int v = (t >= off) ? ls[t - off] : 0;
        __syncthreads();
        ls[t] += v;
        __syncthreads();
    }
    int run = (t == 0) ? 0 : ls[t - 1];
    for (int j = 0; j < chunk; ++j) {
        int i = t + j * 256;
        if (i < NN) { offs[i] = run; cursor[i] = run; run += cnt[i]; }
    }
}

__global__ void scatter_kernel(const int* __restrict__ path_list,
                               int* __restrict__ cursor,
                               int* __restrict__ sorted) {
    int p = blockIdx.x * 256 + threadIdx.x;
    if (p < PP) {
        int row = path_list[p * LL + (LL - 1)];
        int k = atomicAdd(&cursor[row], 1);
        sorted[k] = p;
    }
}

// ---------------------------------------------------------------------------
// gi GEMM: gi[node][d][c] = x[node] @ W_ih[c*128+d] + biases (fused).
// Layout [node][128][3] fp32 packed.
// ---------------------------------------------------------------------------
__global__ __launch_bounds__(512, 2)
void gi_gemm_kernel(const float* __restrict__ x,     // [N][128]
                    const float* __restrict__ w_ih,  // [384][128]
                    const float* __restrict__ b_ih,
                    const float* __restrict__ b_hh,
                    float* __restrict__ gi)          // [N][128][3]
{
    const int tid  = threadIdx.x;
    const int lane = tid & 63;
    const int wave = tid >> 6;
    const int lcol = lane & 15;
    const int quad = lane >> 4;
    const int ko   = quad * 8;
    const int d    = wave * 16 + lcol;
    const int r0   = blockIdx.x * 64;

    short8 B[3][4];
    float bias[3];
    #pragma unroll
    for (int c = 0; c < 3; ++c) {
        int col = c * 128 + d;
        #pragma unroll
        for (int ks = 0; ks < 4; ++ks) {
            const float4* src = (const float4*)(w_ih + (size_t)col * 128 + ks * 32 + ko);
            float4 f0 = src[0], f1 = src[1];
            short8 b;
            b[0] = (short)f2bf(f0.x); b[1] = (short)f2bf(f0.y);
            b[2] = (short)f2bf(f0.z); b[3] = (short)f2bf(f0.w);
            b[4] = (short)f2bf(f1.x); b[5] = (short)f2bf(f1.y);
            b[6] = (short)f2bf(f1.z); b[7] = (short)f2bf(f1.w);
            B[c][ks] = b;
        }
        bias[c] = b_ih[col] + ((c < 2) ? b_hh[col] : 0.f);
    }

    f32x4 acc[3][4];
    #pragma unroll
    for (int c = 0; c < 3; ++c)
        #pragma unroll
        for (int rt = 0; rt < 4; ++rt)
            acc[c][rt] = (f32x4){bias[c], bias[c], bias[c], bias[c]};

    #pragma unroll
    for (int ks = 0; ks < 4; ++ks) {
        #pragma unroll
        for (int rt = 0; rt < 4; ++rt) {
            int row = r0 + rt * 16 + lcol;
            if (row >= NN) row = NN - 1;          // clamp loads, stores guarded
            const float4* src = (const float4*)(x + (size_t)row * 128 + ks * 32 + ko);
            float4 f0 = src[0], f1 = src[1];
            short8 av;
            av[0] = (short)f2bf(f0.x); av[1] = (short)f2bf(f0.y);
            av[2] = (short)f2bf(f0.z); av[3] = (short)f2bf(f0.w);
            av[4] = (short)f2bf(f1.x); av[5] = (short)f2bf(f1.y);
            av[6] = (short)f2bf(f1.z); av[7] = (short)f2bf(f1.w);
            acc[0][rt] = __builtin_amdgcn_mfma_f32_16x16x32_bf16(av, B[0][ks], acc[0][rt], 0, 0, 0);
            acc[1][rt] = __builtin_amdgcn_mfma_f32_16x16x32_bf16(av, B[1][ks], acc[1][rt], 0, 0, 0);
            acc[2][rt] = __builtin_amdgcn_mfma_f32_16x16x32_bf16(av, B[2][ks], acc[2][rt], 0, 0, 0);
        }
    }

    #pragma unroll
    for (int rt = 0; rt < 4; ++rt)
        #pragma unroll
        for (int rr = 0; rr < 4; ++rr) {
            int row = r0 + rt * 16 + quad * 4 + rr;
            if (row < NN) {
                float* o = gi + (size_t)row * 384 + d * 3;
                o[0] = acc[0][rt][rr];
                o[1] = acc[1][rt][rr];
                o[2] = acc[2][rt][rr];
            }
        }
}

// ---------------------------------------------------------------------------
// Per-step GRU kernel (t = 1..5). Fully parallel: 6250 independent WGs/step;
// the inter-step dependency is the kernel boundary (global sync), NOT an
// in-kernel barrier chain — this removes the 13k-cycle/step serialization
// wall of the persistent-kernel design (r0-r5).
//  - FIRST (t=1): stage computes h1 = f(gi[node0]) inline (t=0 folded).
//    Otherwise stage loads h_{t-1} rows from H (in-place buffer; each WG
//    reads only the rows it later writes -> one buffer, no races).
//  - h tile staged to LDS with r0's XOR swizzle; ONE barrier per WG.
//  - gi gather (8 dwordx3/lane) issued after barrier, consumed only in the
//    epilogue (acc init 0/bhn, gate values added post-MFMA) -> gather
//    latency hides under the MFMA phase.
//  - LAST (t=5): r0's proven fp32 attention tail (hs_f alias + red_s),
//    emb written from hs_f (coalesced uint4), att_un/att_sum emitted.
//  - arch-VGPR demand ~105 (Bh 48 + g 24 + addr) <= 128 arch half -> no
//    spill under (512,2) per the 6-round allocator model.
// ---------------------------------------------------------------------------
template <bool FIRST, bool LAST>
__global__ __launch_bounds__(NT, 2)
void gru_step_kernel(const float* __restrict__ gi,            // [N][128][3] fp32
                     const int*   __restrict__ path_list,
                     const unsigned short* __restrict__ whb,  // [384][128] bf16
                     const float* __restrict__ b_hh,
                     const float* __restrict__ a,             // [128][4]
                     unsigned short* __restrict__ H,          // [P][128] bf16 (in/out; final = emb)
                     float* __restrict__ att_sum,             // [N][4]
                     float* __restrict__ att_un_g,            // [P][4]
                     int t)
{
    // smem layout:
    //  non-LAST: hs [0,8192) | nodes_s [8192,8320)
    //  LAST:     hs [0,8192); hs_f fp32 alias [0,16896); red_s [16896,25088);
    //            nodes_s [25088,25216)
    constexpr int SM_BYTES = LAST ? 25216 : 8320;
    __shared__ __align__(16) unsigned char smem[SM_BYTES];
    unsigned short* hs      = (unsigned short*)smem;
    float*          hs_f    = (float*)smem;                       // LAST only
    float*          red_s   = (float*)(smem + 16896);             // LAST only
    int*            nodes_s = (int*)(smem + (LAST ? 25088 : 8192));

    const int tid  = threadIdx.x;
    const int lane = tid & 63;
    const int wave = tid >> 6;
    const int lcol = lane & 15;
    const int quad = lane >> 4;
    const int d    = wave * 16 + lcol;
    const int p0   = blockIdx.x * TM;
    const int ko   = quad * 8;

    // ---- persistent h-side B fragments (48 VGPRs), L2-hot
    short8 Bh[3][4];
    #pragma unroll
    for (int c = 0; c < 3; ++c)
        #pragma unroll
        for (int ks = 0; ks < 4; ++ks)
            Bh[c][ks] = *(const short8*)(whb + (size_t)(c * DD + d) * DD + ks * 32 + ko);
    const float bhn = b_hh[d + 256];

    // ---- stage h_{t-1} tile -> LDS (XOR-swizzled, r0 layout)
    {
        const int gpi = tid >> 4;     // local row 0..31
        const int tt  = tid & 15;     // col-block (8 cols each)
        const int gpm = gpi & 15;
        if (FIRST) {
            // t=0 folded: h1 = (1-z)*n from gi[node0], computed in fp32
            int n0 = path_list[(size_t)(p0 + gpi) * LL + 0];
            const float* gsrc = gi + (size_t)n0 * 384 + (tt * 8) * 3;
            unsigned short pk[8];
            #pragma unroll
            for (int j = 0; j < 8; ++j) {
                f3 gv = *(const f3*)(gsrc + j * 3);
                int col = tt * 8 + j;
                float rr = fast_sigmoid(gv.x);
                float zz = fast_sigmoid(gv.y);
                float nn = fast_tanh(gv.z + rr * b_hh[256 + col]);
                pk[j] = f2bf((1.f - zz) * nn);
            }
            *(uint4*)(hs + gpi * DD + ((tt ^ gpm) * 8)) = *(uint4*)pk;
        } else {
            uint4 v = *(const uint4*)(H + (size_t)(p0 + gpi) * DD + tt * 8);
            *(uint4*)(hs + gpi * DD + ((tt ^ gpm) * 8)) = v;
        }
    }
    if (tid < TM) nodes_s[tid] = path_list[(size_t)(p0 + tid) * LL + t];
    __syncthreads();

    // ---- gi gather (consumed only in epilogue; latency hides under MFMA)
    f3 g[8];
    #pragma unroll
    for (int rt = 0; rt < 2; ++rt)
        #pragma unroll
        for (int r = 0; r < 4; ++r) {
            const int p = rt * 16 + quad * 4 + r;
            g[rt * 4 + r] = *(const f3*)(gi + (size_t)nodes_s[p] * 384 + d * 3);
        }

    f32x4 accR[2], accZ[2], accH[2];
    #pragma unroll
    for (int rt = 0; rt < 2; ++rt) {
        accR[rt] = (f32x4){0.f, 0.f, 0.f, 0.f};
        accZ[rt] = (f32x4){0.f, 0.f, 0.f, 0.f};
        accH[rt] = (f32x4){bhn, bhn, bhn, bhn};
    }

    // ---- MFMA: 24 per wave, operands from LDS
    #pragma unroll
    for (int ks = 0; ks < 4; ++ks) {
        const int kb = ks * 4 + quad;
        #pragma unroll
        for (int rt = 0; rt < 2; ++rt) {
            const int p = rt * 16 + lcol;
            short8 ah = *(const short8*)(hs + p * DD + ((kb ^ lcol) * 8));
            accR[rt] = __builtin_amdgcn_mfma_f32_16x16x32_bf16(ah, Bh[0][ks], accR[rt], 0, 0, 0);
            accZ[rt] = __builtin_amdgcn_mfma_f32_16x16x32_bf16(ah, Bh[1][ks], accZ[rt], 0, 0, 0);
            accH[rt] = __builtin_amdgcn_mfma_f32_16x16x32_bf16(ah, Bh[2][ks], accH[rt], 0, 0, 0);
        }
    }

    // ---- GRU epilogue: gates + h_new (h_prev re-read from LDS)
    float hn8[8];
    #pragma unroll
    for (int rt = 0; rt < 2; ++rt)
        #pragma unroll
        for (int r = 0; r < 4; ++r) {
            const int idx = rt * 4 + r;
            const int p   = rt * 16 + quad * 4 + r;
            float hprev = bf2f(hs[p * DD + (((d >> 3) ^ (p & 15)) * 8) + (d & 7)]);
            float rg = fast_sigmoid(accR[rt][r] + g[idx].x);
            float zg = fast_sigmoid(accZ[rt][r] + g[idx].y);
            float ng = fast_tanh(g[idx].z + rg * accH[rt][r]);
            hn8[idx] = fmaf(zg, hprev - ng, ng);
        }

    if (!LAST) {
        #pragma unroll
        for (int rt = 0; rt < 2; ++rt)
            #pragma unroll
            for (int r = 0; r < 4; ++r) {
                const int p = rt * 16 + quad * 4 + r;
                H[(size_t)(p0 + p) * DD + d] = f2bf(hn8[rt * 4 + r]);
            }
    } else {
        __syncthreads();   // hs_f aliases hs: all LDS reads done first
        #pragma unroll
        for (int rt = 0; rt < 2; ++rt)
            #pragma unroll
            for (int r = 0; r < 4; ++r) {
                const int p = rt * 16 + quad * 4 + r;
                hs_f[p * HPAD + d] = hn8[rt * 4 + r];
            }
        __syncthreads();

        // attention logits + emit bf16 path embedding (into H = emb buffer)
        {
            int pi = tid >> 4, tt = tid & 15;
            float s0 = 0.f, s1 = 0.f, s2 = 0.f, s3 = 0.f;
            unsigned short pack[8];
            #pragma unroll
            for (int j = 0; j < 8; ++j) {
                int dd2 = tt * 8 + j;
                float hv = hs_f[pi * HPAD + dd2];
                pack[j] = f2bf(hv);
                float4 av = *(const float4*)(a + dd2 * 4);
                s0 += hv * av.x; s1 += hv * av.y; s2 += hv * av.z; s3 += hv * av.w;
            }
            *(uint4*)(H + (size_t)(p0 + pi) * DD + tt * 8) = *(uint4*)&pack[0];
            float* rp = red_s + (pi * 16 + tt) * 4;
            rp[0] = s0; rp[1] = s1; rp[2] = s2; rp[3] = s3;
        }
        __syncthreads();
        if (tid < TM) {
            int pi = tid;
            int row = nodes_s[pi];   // node at t=5 == destination row
            float4 e4;
            #pragma unroll
            for (int h = 0; h < HH; ++h) {
                float s = 0.f;
                #pragma unroll
                for (int tt = 0; tt < 16; ++tt) s += red_s[(pi * 16 + tt) * 4 + h];
                float lv = (s > 0.f) ? s : 0.2f * s;
                float e  = __expf(lv);
                ((float*)&e4)[h] = e;
                atomicAdd(&att_sum[row * HH + h], e);
            }
            *(float4*)(att_un_g + (size_t)(p0 + pi) * HH) = e4;
        }
    }
}

// ---------------------------------------------------------------------------
// Pass B: per-node aggregation over its sorted paths. Atomic-free.
// ---------------------------------------------------------------------------
__global__ __launch_bounds__(256)
void agg_kernel(const unsigned short* __restrict__ emb,   // [P][128] bf16
                const float* __restrict__ att_un,         // [P][4]
                const float* __restrict__ att_sum,        // [N][4]
                const int* __restrict__ offs,
                const int* __restrict__ cnt,
                const int* __restrict__ sorted,
                float* __restrict__ out)                  // [N][512]
{
    int node = blockIdx.x * 2 + (threadIdx.x >> 7);
    int d    = threadIdx.x & 127;
    if (node >= NN) return;
    int start = offs[node];
    int len   = cnt[node];
    float a0 = 0.f, a1 = 0.f, a2 = 0.f, a3 = 0.f;
    for (int i = 0; i < len; ++i) {
        int p = sorted[start + i];
        float4 at = *(const float4*)(att_un + (size_t)p * 4);
        float ev = bf2f(emb[(size_t)p * DD + d]);
        a0 = fmaf(at.x, ev, a0);
        a1 = fmaf(at.y, ev, a1);
        a2 = fmaf(at.z, ev, a2);
        a3 = fmaf(at.w, ev, a3);
    }
    float4 s = *(const float4*)(att_sum + (size_t)node * 4);
    float* o = out + (size_t)node * 512 + d;
    o[0]   = (s.x > 0.f) ? a0 / s.x : 0.f;
    o[128] = (s.y > 0.f) ? a1 / s.y : 0.f;
    o[256] = (s.z > 0.f) ? a2 / s.z : 0.f;
    o[384] = (s.w > 0.f) ? a3 / s.w : 0.f;
}

extern "C" void kernel_launch(void* const* d_in, const int* in_sizes, int n_in,
                              void* d_out, int out_size, void* d_ws, size_t ws_size,
                              hipStream_t stream) {
    const float* x         = (const float*)d_in[0];
    const int*   path_list = (const int*)  d_in[1];
    const float* w_ih      = (const float*)d_in[2];
    const float* w_hh      = (const float*)d_in[3];
    const float* b_ih      = (const float*)d_in[4];
    const float* b_hh      = (const float*)d_in[5];
    const float* a         = (const float*)d_in[6];
    float* out = (float*)d_out;

    // workspace layout, total ~133.5 MB (same footprint as the r1 build)
    char* w = (char*)d_ws;
    float*          att_sum = (float*)w;                 w += 800000;       // N*4 f32
    int*            cnt     = (int*)w;                   w += 200000;       // N
    int*            offs    = (int*)w;                   w += 200000;       // N
    int*            cursor  = (int*)w;                   w += 200000;       // N
    int*            sorted  = (int*)w;                   w += 800000;       // P
    float*          att_un  = (float*)w;                 w += 3200000;      // P*4 f32
    float*          gi      = (float*)w;                 w += 76800000;     // N*128*3 f32
    unsigned short* whb     = (unsigned short*)w;        w += 98304;        // 384*128 bf16
    unsigned short* H       = (unsigned short*)w;        w += 51200000;     // P*128 bf16 (h state; final = emb)

    hipMemsetAsync(att_sum, 0, 800000, stream);
    hipMemsetAsync(cnt, 0, 200000, stream);

    prep_w_kernel<<<(3 * DD * DD + 255) / 256, 256, 0, stream>>>(w_hh, whb);

    histo_kernel<<<(PP + 255) / 256, 256, 0, stream>>>(path_list, cnt);
    scan_kernel<<<1, 256, 0, stream>>>(cnt, offs, cursor);
    scatter_kernel<<<(PP + 255) / 256, 256, 0, stream>>>(path_list, cursor, sorted);

    gi_gemm_kernel<<<(NN + 63) / 64, 512, 0, stream>>>(x, w_ih, b_ih, b_hh, gi);

    // 5 parallel GRU steps; t=0 folded into t=1's stage; t=5 carries att tail
    gru_step_kernel<true,  false><<<PP / TM, NT, 0, stream>>>(gi, path_list, whb, b_hh, a, H, att_sum, att_un, 1);
    gru_step_kernel<false, false><<<PP / TM, NT, 0, stream>>>(gi, path_list, whb, b_hh, a, H, att_sum, att_un, 2);
    gru_step_kernel<false, false><<<PP / TM, NT, 0, stream>>>(gi, path_list, whb, b_hh, a, H, att_sum, att_un, 3);
    gru_step_kernel<false, false><<<PP / TM, NT, 0, stream>>>(gi, path_list, whb, b_hh, a, H, att_sum, att_un, 4);
    gru_step_kernel<false, true ><<<PP / TM, NT, 0, stream>>>(gi, path_list, whb, b_hh, a, H, att_sum, att_un, 5);

    agg_kernel<<<(NN + 1) / 2, 256, 0, stream>>>(H, att_un, att_sum,
                                                 offs, cnt, sorted, out);
}

// Round 7
// 736.795 us; speedup vs baseline: 1.2447x; 1.1663x over previous
//
#include <hip/hip_runtime.h>
#include <hip/hip_bf16.h>
#include <math.h>

// Problem constants
#define NN 50000
#define PP 200000
#define LL 6
#define DD 128      // IN_DIM == OUT_DIM
#define HH 4        // heads

// Tiling
#define TM 64       // paths per workgroup
#define NT 512      // threads per workgroup (8 waves)
#define HPAD 132    // fp32 row stride for final-h LDS (bank spread)

typedef __attribute__((ext_vector_type(8))) short short8;   // 8 bf16 (MFMA A/B frag)
typedef __attribute__((ext_vector_type(4))) float f32x4;    // MFMA C/D frag

__device__ __forceinline__ unsigned short f2bf(float v) {
    __hip_bfloat16 h = __float2bfloat16(v);
    return *(unsigned short*)&h;
}
__device__ __forceinline__ float bf2f(unsigned short u) {
    union { unsigned int i; float f; } c; c.i = ((unsigned int)u) << 16; return c.f;
}
__device__ __forceinline__ unsigned short f2h(float v) {
    _Float16 h = (_Float16)v;
    return *(unsigned short*)&h;
}
__device__ __forceinline__ float h2f(unsigned short u) {
    _Float16 h = *(_Float16*)&u;
    return (float)h;
}
__device__ __forceinline__ float fast_rcp(float x) { return __builtin_amdgcn_rcpf(x); }
__device__ __forceinline__ float fast_sigmoid(float x) {
    return fast_rcp(1.f + __expf(-x));
}
__device__ __forceinline__ float fast_tanh(float x) {
    float e = __expf(-2.f * fabsf(x));
    float t = (1.f - e) * fast_rcp(1.f + e);
    return copysignf(t, x);
}

// ---------------------------------------------------------------------------
// Prep: cast W_hh to bf16.
// ---------------------------------------------------------------------------
__global__ void prep_w_kernel(const float* __restrict__ w_hh,
                              unsigned short* __restrict__ whb) {
    int i = blockIdx.x * 256 + threadIdx.x;
    if (i < 3 * DD * DD) whb[i] = f2bf(w_hh[i]);
}

// ---------------------------------------------------------------------------
// Counting sort of paths by destination row (= path_list[p][5]).
// ---------------------------------------------------------------------------
__global__ void histo_kernel(const int* __restrict__ path_list,
                             int* __restrict__ cnt) {
    int p = blockIdx.x * 256 + threadIdx.x;
    if (p < PP) atomicAdd(&cnt[path_list[p * LL + (LL - 1)]], 1);
}

__global__ void scan_kernel(const int* __restrict__ cnt,
                            int* __restrict__ offs,
                            int* __restrict__ cursor) {
    __shared__ int ls[256];
    const int t = threadIdx.x;
    const int chunk = (NN + 255) / 256;
    int s = 0;
    for (int j = 0; j < chunk; ++j) {
        int i = t + j * 256;
        if (i < NN) s += cnt[i];
    }
    ls[t] = s; __syncthreads();
    for (int off = 1; off < 256; off <<= 1) {
        int v = (t >= off) ? ls[t - off] : 0;
        __syncthreads();
        ls[t] += v;
        __syncthreads();
    }
    int run = (t == 0) ? 0 : ls[t - 1];
    for (int j = 0; j < chunk; ++j) {
        int i = t + j * 256;
        if (i < NN) { offs[i] = run; cursor[i] = run; run += cnt[i]; }
    }
}

__global__ void scatter_kernel(const int* __restrict__ path_list,
                               int* __restrict__ cursor,
                               int* __restrict__ sorted) {
    int p = blockIdx.x * 256 + threadIdx.x;
    if (p < PP) {
        int row = path_list[p * LL + (LL - 1)];
        int k = atomicAdd(&cursor[row], 1);
        sorted[k] = p;
    }
}

// ---------------------------------------------------------------------------
// gi GEMM: x-side gate pre-activations, biases fused, stored FP16:
//   giRZ[node][d] = pack_fp16(ir + b_ih_r + b_hh_r, iz + b_ih_z + b_hh_z)
//   giN [node][d] = fp16(in + b_ih_n)
// Halves the GRU kernel's gather bytes vs fp32 [node][128][3] (the r1->r7
// single-variable change testing the gather-BW hypothesis).
// ---------------------------------------------------------------------------
__global__ __launch_bounds__(512, 2)
void gi_gemm_kernel(const float* __restrict__ x,     // [N][128]
                    const float* __restrict__ w_ih,  // [384][128]
                    const float* __restrict__ b_ih,
                    const float* __restrict__ b_hh,
                    unsigned int*   __restrict__ giRZ,   // [N][128] u32 (2x fp16)
                    unsigned short* __restrict__ giN)    // [N][128] fp16
{
    const int tid  = threadIdx.x;
    const int lane = tid & 63;
    const int wave = tid >> 6;
    const int lcol = lane & 15;
    const int quad = lane >> 4;
    const int ko   = quad * 8;
    const int d    = wave * 16 + lcol;
    const int r0   = blockIdx.x * 64;

    short8 B[3][4];
    float bias[3];
    #pragma unroll
    for (int c = 0; c < 3; ++c) {
        int col = c * 128 + d;
        #pragma unroll
        for (int ks = 0; ks < 4; ++ks) {
            const float4* src = (const float4*)(w_ih + (size_t)col * 128 + ks * 32 + ko);
            float4 f0 = src[0], f1 = src[1];
            short8 b;
            b[0] = (short)f2bf(f0.x); b[1] = (short)f2bf(f0.y);
            b[2] = (short)f2bf(f0.z); b[3] = (short)f2bf(f0.w);
            b[4] = (short)f2bf(f1.x); b[5] = (short)f2bf(f1.y);
            b[6] = (short)f2bf(f1.z); b[7] = (short)f2bf(f1.w);
            B[c][ks] = b;
        }
        bias[c] = b_ih[col] + ((c < 2) ? b_hh[col] : 0.f);
    }

    f32x4 acc[3][4];
    #pragma unroll
    for (int c = 0; c < 3; ++c)
        #pragma unroll
        for (int rt = 0; rt < 4; ++rt)
            acc[c][rt] = (f32x4){bias[c], bias[c], bias[c], bias[c]};

    #pragma unroll
    for (int ks = 0; ks < 4; ++ks) {
        #pragma unroll
        for (int rt = 0; rt < 4; ++rt) {
            int row = r0 + rt * 16 + lcol;
            if (row >= NN) row = NN - 1;          // clamp loads, stores guarded
            const float4* src = (const float4*)(x + (size_t)row * 128 + ks * 32 + ko);
            float4 f0 = src[0], f1 = src[1];
            short8 av;
            av[0] = (short)f2bf(f0.x); av[1] = (short)f2bf(f0.y);
            av[2] = (short)f2bf(f0.z); av[3] = (short)f2bf(f0.w);
            av[4] = (short)f2bf(f1.x); av[5] = (short)f2bf(f1.y);
            av[6] = (short)f2bf(f1.z); av[7] = (short)f2bf(f1.w);
            acc[0][rt] = __builtin_amdgcn_mfma_f32_16x16x32_bf16(av, B[0][ks], acc[0][rt], 0, 0, 0);
            acc[1][rt] = __builtin_amdgcn_mfma_f32_16x16x32_bf16(av, B[1][ks], acc[1][rt], 0, 0, 0);
            acc[2][rt] = __builtin_amdgcn_mfma_f32_16x16x32_bf16(av, B[2][ks], acc[2][rt], 0, 0, 0);
        }
    }

    #pragma unroll
    for (int rt = 0; rt < 4; ++rt)
        #pragma unroll
        for (int rr = 0; rr < 4; ++rr) {
            int row = r0 + rt * 16 + quad * 4 + rr;
            if (row < NN) {
                unsigned int rz = (unsigned int)f2h(acc[0][rt][rr])
                                | ((unsigned int)f2h(acc[1][rt][rr]) << 16);
                giRZ[(size_t)row * 128 + d] = rz;
                giN [(size_t)row * 128 + d] = f2h(acc[2][rt][rr]);
            }
        }
}

// ---------------------------------------------------------------------------
// Pass A: h-side-only MFMA GRU — EXACT r1 structure (420 us, VGPR 128, no
// spill), with ONE change: gi gather is fp16-packed (1 dword + 1 ushort per
// (path,d) = 6B instead of 12B) -> logical gather 1.84 GB -> 0.92 GB.
// Tests the hypothesis that r1's GRU is gi-gather-byte-bound.
// ---------------------------------------------------------------------------
__global__ __launch_bounds__(NT, 2)
void gru_att_kernel(const unsigned int*   __restrict__ giRZ,  // [N][128] u32
                    const unsigned short* __restrict__ giN,   // [N][128] fp16
                    const int*   __restrict__ path_list,
                    const unsigned short* __restrict__ whb,   // [384][128] bf16
                    const float* __restrict__ b_hh,
                    const float* __restrict__ a,              // [128][4]
                    float* __restrict__ att_sum,              // [N][4]
                    unsigned short* __restrict__ emb,         // [P][128] bf16
                    float* __restrict__ att_un_g)             // [P][4]
{
    // smem: [0,16384) hs0 | [16384,32768) hs1 | hs_f fp32 aliases [0,33792)
    //       [33792,41984) red_s | [41984,43520) nodes_s
    __shared__ __align__(16) unsigned char smem[43520];
    unsigned short* hs0    = (unsigned short*)smem;
    unsigned short* hs1    = (unsigned short*)(smem + 16384);
    float*          hs_f   = (float*)smem;                 // alias (final step only)
    float*          red_s  = (float*)(smem + 33792);       // [64][8][4]
    int*            nodes_s= (int*)(smem + 41984);         // [TM*LL]

    const int tid  = threadIdx.x;
    const int lane = tid & 63;
    const int wave = tid >> 6;
    const int lcol = lane & 15;
    const int quad = lane >> 4;
    const int d    = wave * 16 + lcol;
    const int p0   = blockIdx.x * TM;
    const int ko   = quad * 8;

    // persistent h-side B fragments (c=0:r, 1:z, 2:n)
    short8 Bh[3][4];
    #pragma unroll
    for (int c = 0; c < 3; ++c)
        #pragma unroll
        for (int ks = 0; ks < 4; ++ks)
            Bh[c][ks] = *(const short8*)(whb + (size_t)(c * DD + d) * DD + ks * 32 + ko);
    const float bhn = b_hh[d + 256];

    for (int i = tid; i < TM * LL; i += NT) nodes_s[i] = path_list[(size_t)p0 * LL + i];
    for (int i = tid; i < TM * DD / 8; i += NT)
        ((uint4*)hs0)[i] = make_uint4(0u, 0u, 0u, 0u);

    float hreg[16];
    #pragma unroll
    for (int i = 0; i < 16; ++i) hreg[i] = 0.f;

    __syncthreads();   // nodes_s + hs0 zero visible

    #pragma unroll 1
    for (int t = 0; t < LL; ++t) {
        unsigned short* hr = (t & 1) ? hs1 : hs0;   // read buffer
        unsigned short* hw = (t & 1) ? hs0 : hs1;   // write buffer

        // fp16 gi loads -> direct accumulator init (biases folded in gi).
        float gin[16];
        f32x4 accR[4], accZ[4], accH[4];
        #pragma unroll
        for (int rt = 0; rt < 4; ++rt)
            #pragma unroll
            for (int r = 0; r < 4; ++r) {
                const int p = rt * 16 + quad * 4 + r;
                const int node = nodes_s[p * LL + t];
                unsigned int rz   = giRZ[(size_t)node * 128 + d];
                unsigned short nn = giN [(size_t)node * 128 + d];
                accR[rt][r] = h2f((unsigned short)(rz & 0xffffu));
                accZ[rt][r] = h2f((unsigned short)(rz >> 16));
                gin[rt * 4 + r] = h2f(nn);
            }
        #pragma unroll
        for (int rt = 0; rt < 4; ++rt)
            accH[rt] = (f32x4){bhn, bhn, bhn, bhn};

        // MFMA: h-side only (48 MFMAs, 16 ds_read_b128 per wave)
        #pragma unroll
        for (int ks = 0; ks < 4; ++ks) {
            const int kb = ks * 4 + quad;
            #pragma unroll
            for (int rt = 0; rt < 4; ++rt) {
                const int p = rt * 16 + lcol;
                short8 ah = *(const short8*)(hr + p * DD + ((kb ^ lcol) * 8));
                accR[rt] = __builtin_amdgcn_mfma_f32_16x16x32_bf16(ah, Bh[0][ks], accR[rt], 0, 0, 0);
                accZ[rt] = __builtin_amdgcn_mfma_f32_16x16x32_bf16(ah, Bh[1][ks], accZ[rt], 0, 0, 0);
                accH[rt] = __builtin_amdgcn_mfma_f32_16x16x32_bf16(ah, Bh[2][ks], accH[rt], 0, 0, 0);
            }
        }

        if (t == LL - 1) __syncthreads();  // hs_f aliases hs0/hs1: reads done first

        // GRU cell epilogue
        #pragma unroll
        for (int rt = 0; rt < 4; ++rt) {
            #pragma unroll
            for (int r = 0; r < 4; ++r) {
                const int idx = rt * 4 + r;
                const int p   = rt * 16 + quad * 4 + r;
                float rg = fast_sigmoid(accR[rt][r]);
                float zg = fast_sigmoid(accZ[rt][r]);
                float ng = fast_tanh(gin[idx] + rg * accH[rt][r]);  // accH = hn + b_hh_n
                float hnew = fmaf(zg, hreg[idx] - ng, ng);
                hreg[idx] = hnew;
                if (t < LL - 1) {
                    hw[p * DD + (((d >> 3) ^ (p & 15)) * 8) + (d & 7)] = f2bf(hnew);
                } else {
                    hs_f[p * HPAD + d] = hnew;   // fp32, aliases dead hs buffers
                }
            }
        }
        __syncthreads();   // hw complete (and, at t=5, hs_f complete)
    }

    // attention logits + emit bf16 path embedding
    {
        int pi = tid >> 3, tt = tid & 7;
        float s0 = 0.f, s1 = 0.f, s2 = 0.f, s3 = 0.f;
        unsigned short pack[16];
        #pragma unroll
        for (int j = 0; j < 16; ++j) {
            int dd2 = tt * 16 + j;
            float hv = hs_f[pi * HPAD + dd2];
            pack[j] = f2bf(hv);
            float4 av = *(const float4*)(a + dd2 * 4);
            s0 += hv * av.x; s1 += hv * av.y; s2 += hv * av.z; s3 += hv * av.w;
        }
        uint4* dst = (uint4*)(emb + (size_t)(p0 + pi) * DD + tt * 16);
        dst[0] = *(uint4*)&pack[0];
        dst[1] = *(uint4*)&pack[8];
        float* rp = red_s + (pi * 8 + tt) * 4;
        rp[0] = s0; rp[1] = s1; rp[2] = s2; rp[3] = s3;
    }
    __syncthreads();
    if (tid < TM) {
        int pi = tid;
        int row = nodes_s[pi * LL + (LL - 1)];
        float4 e4;
        #pragma unroll
        for (int h = 0; h < HH; ++h) {
            float s = 0.f;
            #pragma unroll
            for (int tt = 0; tt < 8; ++tt) s += red_s[(pi * 8 + tt) * 4 + h];
            float lv = (s > 0.f) ? s : 0.2f * s;
            float e  = __expf(lv);
            ((float*)&e4)[h] = e;
            atomicAdd(&att_sum[row * HH + h], e);
        }
        *(float4*)(att_un_g + (size_t)(p0 + pi) * HH) = e4;
    }
}

// ---------------------------------------------------------------------------
// Pass B: per-node aggregation over its sorted paths. Atomic-free.
// ---------------------------------------------------------------------------
__global__ __launch_bounds__(256)
void agg_kernel(const unsigned short* __restrict__ emb,   // [P][128] bf16
                const float* __restrict__ att_un,         // [P][4]
                const float* __restrict__ att_sum,        // [N][4]
                const int* __restrict__ offs,
                const int* __restrict__ cnt,
                const int* __restrict__ sorted,
                float* __restrict__ out)                  // [N][512]
{
    int node = blockIdx.x * 2 + (threadIdx.x >> 7);
    int d    = threadIdx.x & 127;
    if (node >= NN) return;
    int start = offs[node];
    int len   = cnt[node];
    float a0 = 0.f, a1 = 0.f, a2 = 0.f, a3 = 0.f;
    for (int i = 0; i < len; ++i) {
        int p = sorted[start + i];
        float4 at = *(const float4*)(att_un + (size_t)p * 4);
        float ev = bf2f(emb[(size_t)p * DD + d]);
        a0 = fmaf(at.x, ev, a0);
        a1 = fmaf(at.y, ev, a1);
        a2 = fmaf(at.z, ev, a2);
        a3 = fmaf(at.w, ev, a3);
    }
    float4 s = *(const float4*)(att_sum + (size_t)node * 4);
    float* o = out + (size_t)node * 512 + d;
    o[0]   = (s.x > 0.f) ? a0 / s.x : 0.f;
    o[128] = (s.y > 0.f) ? a1 / s.y : 0.f;
    o[256] = (s.z > 0.f) ? a2 / s.z : 0.f;
    o[384] = (s.w > 0.f) ? a3 / s.w : 0.f;
}

extern "C" void kernel_launch(void* const* d_in, const int* in_sizes, int n_in,
                              void* d_out, int out_size, void* d_ws, size_t ws_size,
                              hipStream_t stream) {
    const float* x         = (const float*)d_in[0];
    const int*   path_list = (const int*)  d_in[1];
    const float* w_ih      = (const float*)d_in[2];
    const float* w_hh      = (const float*)d_in[3];
    const float* b_ih      = (const float*)d_in[4];
    const float* b_hh      = (const float*)d_in[5];
    const float* a         = (const float*)d_in[6];
    float* out = (float*)d_out;

    // workspace layout (all 16B-multiple sizes), total ~95 MB
    char* w = (char*)d_ws;
    float*          att_sum = (float*)w;                 w += 800000;       // N*4 f32
    int*            cnt     = (int*)w;                   w += 200000;       // N
    int*            offs    = (int*)w;                   w += 200000;       // N
    int*            cursor  = (int*)w;                   w += 200000;       // N
    int*            sorted  = (int*)w;                   w += 800000;       // P
    float*          att_un  = (float*)w;                 w += 3200000;      // P*4 f32
    unsigned int*   giRZ    = (unsigned int*)w;          w += 25600000;     // N*128 u32
    unsigned short* giN     = (unsigned short*)w;        w += 12800000;     // N*128 fp16
    unsigned short* whb     = (unsigned short*)w;        w += 98304;        // 384*128 bf16
    unsigned short* emb     = (unsigned short*)w;        w += 51200000;     // P*128 bf16

    hipMemsetAsync(att_sum, 0, 800000, stream);
    hipMemsetAsync(cnt, 0, 200000, stream);

    prep_w_kernel<<<(3 * DD * DD + 255) / 256, 256, 0, stream>>>(w_hh, whb);

    histo_kernel<<<(PP + 255) / 256, 256, 0, stream>>>(path_list, cnt);
    scan_kernel<<<1, 256, 0, stream>>>(cnt, offs, cursor);
    scatter_kernel<<<(PP + 255) / 256, 256, 0, stream>>>(path_list, cursor, sorted);

    gi_gemm_kernel<<<(NN + 63) / 64, 512, 0, stream>>>(x, w_ih, b_ih, b_hh, giRZ, giN);

    gru_att_kernel<<<PP / TM, NT, 0, stream>>>(giRZ, giN, path_list, whb,
                                               b_hh, a, att_sum, emb, att_un);

    agg_kernel<<<(NN + 1) / 2, 256, 0, stream>>>(emb, att_un, att_sum,
                                                 offs, cnt, sorted, out);
}

// Round 8
// 723.088 us; speedup vs baseline: 1.2683x; 1.0190x over previous
//
#include <hip/hip_runtime.h>
#include <hip/hip_bf16.h>
#include <math.h>

// Problem constants
#define NN 50000
#define PP 200000
#define LL 6
#define DD 128      // IN_DIM == OUT_DIM
#define HH 4        // heads

// Tiling
#define TM 64       // paths per workgroup
#define NT 512      // threads per workgroup (8 waves)
#define HPAD 132    // fp32 row stride for final-h LDS (bank spread)

typedef __attribute__((ext_vector_type(8))) short short8;   // 8 bf16 (MFMA A/B frag)
typedef __attribute__((ext_vector_type(4))) float f32x4;    // MFMA C/D frag

__device__ __forceinline__ unsigned short f2bf(float v) {
    __hip_bfloat16 h = __float2bfloat16(v);
    return *(unsigned short*)&h;
}
__device__ __forceinline__ float bf2f(unsigned short u) {
    union { unsigned int i; float f; } c; c.i = ((unsigned int)u) << 16; return c.f;
}
__device__ __forceinline__ unsigned short f2h(float v) {
    _Float16 h = (_Float16)v;
    return *(unsigned short*)&h;
}
__device__ __forceinline__ float h2f(unsigned short u) {
    _Float16 h = *(_Float16*)&u;
    return (float)h;
}
__device__ __forceinline__ float fast_rcp(float x) { return __builtin_amdgcn_rcpf(x); }
__device__ __forceinline__ float fast_sigmoid(float x) {
    return fast_rcp(1.f + __expf(-x));
}
__device__ __forceinline__ float fast_tanh(float x) {
    float e = __expf(-2.f * fabsf(x));
    float t = (1.f - e) * fast_rcp(1.f + e);
    return copysignf(t, x);
}

// async global(per-lane src) -> LDS(wave-uniform base + lane*4), 4B/lane
__device__ __forceinline__ void gload_lds4(const unsigned int* g, unsigned int* l) {
    __builtin_amdgcn_global_load_lds(
        (const __attribute__((address_space(1))) unsigned int*)g,
        (__attribute__((address_space(3))) unsigned int*)l, 4, 0, 0);
}

// ---------------------------------------------------------------------------
// Prep: cast W_hh to bf16.
// ---------------------------------------------------------------------------
__global__ void prep_w_kernel(const float* __restrict__ w_hh,
                              unsigned short* __restrict__ whb) {
    int i = blockIdx.x * 256 + threadIdx.x;
    if (i < 3 * DD * DD) whb[i] = f2bf(w_hh[i]);
}

// ---------------------------------------------------------------------------
// Counting sort of paths by destination row (= path_list[p][5]).
// ---------------------------------------------------------------------------
__global__ void histo_kernel(const int* __restrict__ path_list,
                             int* __restrict__ cnt) {
    int p = blockIdx.x * 256 + threadIdx.x;
    if (p < PP) atomicAdd(&cnt[path_list[p * LL + (LL - 1)]], 1);
}

__global__ void scan_kernel(const int* __restrict__ cnt,
                            int* __restrict__ offs,
                            int* __restrict__ cursor) {
    __shared__ int ls[256];
    const int t = threadIdx.x;
    const int chunk = (NN + 255) / 256;
    int s = 0;
    for (int j = 0; j < chunk; ++j) {
        int i = t + j * 256;
        if (i < NN) s += cnt[i];
    }
    ls[t] = s; __syncthreads();
    for (int off = 1; off < 256; off <<= 1) {
        int v = (t >= off) ? ls[t - off] : 0;
        __syncthreads();
        ls[t] += v;
        __syncthreads();
    }
    int run = (t == 0) ? 0 : ls[t - 1];
    for (int j = 0; j < chunk; ++j) {
        int i = t + j * 256;
        if (i < NN) { offs[i] = run; cursor[i] = run; run += cnt[i]; }
    }
}

__global__ void scatter_kernel(const int* __restrict__ path_list,
                               int* __restrict__ cursor,
                               int* __restrict__ sorted) {
    int p = blockIdx.x * 256 + threadIdx.x;
    if (p < PP) {
        int row = path_list[p * LL + (LL - 1)];
        int k = atomicAdd(&cursor[row], 1);
        sorted[k] = p;
    }
}

// ---------------------------------------------------------------------------
// gi GEMM: x-side gate pre-activations, biases fused, stored FP16:
//   giRZ[node][d] = pack_fp16(r_pre, z_pre)   (u32)
//   giN [node][d] = fp16(n_pre)               (u16; u32-viewable, 2 d per u32)
// ---------------------------------------------------------------------------
__global__ __launch_bounds__(512, 2)
void gi_gemm_kernel(const float* __restrict__ x,     // [N][128]
                    const float* __restrict__ w_ih,  // [384][128]
                    const float* __restrict__ b_ih,
                    const float* __restrict__ b_hh,
                    unsigned int*   __restrict__ giRZ,   // [N][128] u32 (2x fp16)
                    unsigned short* __restrict__ giN)    // [N][128] fp16
{
    const int tid  = threadIdx.x;
    const int lane = tid & 63;
    const int wave = tid >> 6;
    const int lcol = lane & 15;
    const int quad = lane >> 4;
    const int ko   = quad * 8;
    const int d    = wave * 16 + lcol;
    const int r0   = blockIdx.x * 64;

    short8 B[3][4];
    float bias[3];
    #pragma unroll
    for (int c = 0; c < 3; ++c) {
        int col = c * 128 + d;
        #pragma unroll
        for (int ks = 0; ks < 4; ++ks) {
            const float4* src = (const float4*)(w_ih + (size_t)col * 128 + ks * 32 + ko);
            float4 f0 = src[0], f1 = src[1];
            short8 b;
            b[0] = (short)f2bf(f0.x); b[1] = (short)f2bf(f0.y);
            b[2] = (short)f2bf(f0.z); b[3] = (short)f2bf(f0.w);
            b[4] = (short)f2bf(f1.x); b[5] = (short)f2bf(f1.y);
            b[6] = (short)f2bf(f1.z); b[7] = (short)f2bf(f1.w);
            B[c][ks] = b;
        }
        bias[c] = b_ih[col] + ((c < 2) ? b_hh[col] : 0.f);
    }

    f32x4 acc[3][4];
    #pragma unroll
    for (int c = 0; c < 3; ++c)
        #pragma unroll
        for (int rt = 0; rt < 4; ++rt)
            acc[c][rt] = (f32x4){bias[c], bias[c], bias[c], bias[c]};

    #pragma unroll
    for (int ks = 0; ks < 4; ++ks) {
        #pragma unroll
        for (int rt = 0; rt < 4; ++rt) {
            int row = r0 + rt * 16 + lcol;
            if (row >= NN) row = NN - 1;          // clamp loads, stores guarded
            const float4* src = (const float4*)(x + (size_t)row * 128 + ks * 32 + ko);
            float4 f0 = src[0], f1 = src[1];
            short8 av;
            av[0] = (short)f2bf(f0.x); av[1] = (short)f2bf(f0.y);
            av[2] = (short)f2bf(f0.z); av[3] = (short)f2bf(f0.w);
            av[4] = (short)f2bf(f1.x); av[5] = (short)f2bf(f1.y);
            av[6] = (short)f2bf(f1.z); av[7] = (short)f2bf(f1.w);
            acc[0][rt] = __builtin_amdgcn_mfma_f32_16x16x32_bf16(av, B[0][ks], acc[0][rt], 0, 0, 0);
            acc[1][rt] = __builtin_amdgcn_mfma_f32_16x16x32_bf16(av, B[1][ks], acc[1][rt], 0, 0, 0);
            acc[2][rt] = __builtin_amdgcn_mfma_f32_16x16x32_bf16(av, B[2][ks], acc[2][rt], 0, 0, 0);
        }
    }

    #pragma unroll
    for (int rt = 0; rt < 4; ++rt)
        #pragma unroll
        for (int rr = 0; rr < 4; ++rr) {
            int row = r0 + rt * 16 + quad * 4 + rr;
            if (row < NN) {
                unsigned int rz = (unsigned int)f2h(acc[0][rt][rr])
                                | ((unsigned int)f2h(acc[1][rt][rr]) << 16);
                giRZ[(size_t)row * 128 + d] = rz;
                giN [(size_t)row * 128 + d] = f2h(acc[2][rt][rr]);
            }
        }
}

// ---------------------------------------------------------------------------
// Pass A: h-side-only MFMA GRU with ASYNC gi gather -> LDS (one step ahead).
//  - r7 falsified the byte-bound theory (half bytes, same 448us). The wall
//    is the gather latency exposed at the top of every step (load consumed
//    immediately at acc-init). Register prefetch fixes spilled 3x (r3/r5).
//  - Fix: global_load_lds stages step t+1's gi tile (64x128 rz u32 + n u16)
//    into a double-buffered LDS region at the TOP of step t. Per-lane global
//    src is legal; LDS dest is wave-uniform base + lane*4 by construction.
//    Held-register cost ~0 -> no spill possible. The end-of-step
//    __syncthreads() (drains vmcnt) is the only wait; loads had a full step
//    to land -> drain ~free.
//  - LDS tile strides (132/66 u32 rows) make consumption reads <=2-way
//    bank aliasing (free) and keep async dest rows load-aligned (256B).
//  - LDS total 140.5KB of the 160KB/CU (we are at 1 WG/CU regardless).
// ---------------------------------------------------------------------------
__global__ __launch_bounds__(NT, 2)
void gru_att_kernel(const unsigned int* __restrict__ giRZ,  // [N][128] u32
                    const unsigned int* __restrict__ giN32, // [N][64] u32 (2x fp16)
                    const int*   __restrict__ path_list,
                    const unsigned short* __restrict__ whb,   // [384][128] bf16
                    const float* __restrict__ b_hh,
                    const float* __restrict__ a,              // [128][4]
                    float* __restrict__ att_sum,              // [N][4]
                    unsigned short* __restrict__ emb,         // [P][128] bf16
                    float* __restrict__ att_un_g)             // [P][4]
{
    // smem: [0,16384) hs0 | [16384,32768) hs1
    //       [32768,66560)  gz0 (64 rows x 132 u32)   [66560,100352) gz1
    //       [100352,117248) gn0 (64 rows x 66 u32)   [117248,134144) gn1
    //       [134144,142336) red_s | [142336,143872) nodes_s
    //       hs_f fp32 [0,33792) aliases hs0+hs1+first 1KB of gz0 (dead at t=5)
    __shared__ __align__(16) unsigned char smem[143872];
    unsigned short* hs0    = (unsigned short*)smem;
    unsigned short* hs1    = (unsigned short*)(smem + 16384);
    unsigned int*   gz0    = (unsigned int*)(smem + 32768);
    unsigned int*   gz1    = (unsigned int*)(smem + 66560);
    unsigned int*   gn0    = (unsigned int*)(smem + 100352);
    unsigned int*   gn1    = (unsigned int*)(smem + 117248);
    float*          hs_f   = (float*)smem;                 // alias (final step only)
    float*          red_s  = (float*)(smem + 134144);      // [64][8][4]
    int*            nodes_s= (int*)(smem + 142336);        // [TM*LL]

    const int tid  = threadIdx.x;
    const int lane = tid & 63;
    const int wave = tid >> 6;
    const int lcol = lane & 15;
    const int quad = lane >> 4;
    const int d    = wave * 16 + lcol;
    const int p0   = blockIdx.x * TM;
    const int ko   = quad * 8;

    // persistent h-side B fragments (c=0:r, 1:z, 2:n)
    short8 Bh[3][4];
    #pragma unroll
    for (int c = 0; c < 3; ++c)
        #pragma unroll
        for (int ks = 0; ks < 4; ++ks)
            Bh[c][ks] = *(const short8*)(whb + (size_t)(c * DD + d) * DD + ks * 32 + ko);
    const float bhn = b_hh[d + 256];

    for (int i = tid; i < TM * LL; i += NT) nodes_s[i] = path_list[(size_t)p0 * LL + i];
    __syncthreads();   // nodes visible (prefetch addressing needs all rows)

    // ---- async stage of gi tile for step tt into (gz,gn) ----
    // RZ: half-row hr = wave*16+j -> p=hr>>1, half=hr&1; lane covers 64 u32.
    // N : row p = wave*8+j; lane covers 64 u32 (=128 fp16).
    #define STAGE_GI(gz, gn, tt)                                              \
        {                                                                     \
            _Pragma("unroll")                                                 \
            for (int j = 0; j < 16; ++j) {                                    \
                int hr_ = wave * 16 + j;                                      \
                int pp_ = hr_ >> 1, hf_ = hr_ & 1;                            \
                int nd_ = nodes_s[pp_ * LL + (tt)];                           \
                gload_lds4(giRZ + (size_t)nd_ * 128 + hf_ * 64 + lane,        \
                           (gz) + pp_ * 132 + hf_ * 64);                      \
            }                                                                 \
            _Pragma("unroll")                                                 \
            for (int j = 0; j < 8; ++j) {                                     \
                int pp_ = wave * 8 + j;                                       \
                int nd_ = nodes_s[pp_ * LL + (tt)];                           \
                gload_lds4(giN32 + (size_t)nd_ * 64 + lane,                   \
                           (gn) + pp_ * 66);                                  \
            }                                                                 \
        }

    STAGE_GI(gz0, gn0, 0);   // prefetch t=0

    for (int i = tid; i < TM * DD / 8; i += NT)
        ((uint4*)hs0)[i] = make_uint4(0u, 0u, 0u, 0u);

    float hreg[16];
    #pragma unroll
    for (int i = 0; i < 16; ++i) hreg[i] = 0.f;

    __syncthreads();   // hs0 zero + gi(t=0) landed (vmcnt drained)

    #pragma unroll 1
    for (int t = 0; t < LL; ++t) {
        unsigned short* hr = (t & 1) ? hs1 : hs0;   // read buffer
        unsigned short* hw = (t & 1) ? hs0 : hs1;   // write buffer
        unsigned int*   gzc = (t & 1) ? gz1 : gz0;  // gi tile for this step
        unsigned int*   gnc = (t & 1) ? gn1 : gn0;

        // issue async gather for t+1 into the opposite buffers (no regs held)
        if (t < LL - 1) {
            if (t & 1) { STAGE_GI(gz0, gn0, t + 1); }
            else       { STAGE_GI(gz1, gn1, t + 1); }
        }

        // acc init from the LDS gi tile (ds_read, ~free latency)
        float gin[16];
        f32x4 accR[4], accZ[4], accH[4];
        #pragma unroll
        for (int rt = 0; rt < 4; ++rt) {
            #pragma unroll
            for (int r = 0; r < 4; ++r) {
                const int p = rt * 16 + quad * 4 + r;
                unsigned int rz   = gzc[p * 132 + d];
                unsigned short nn = ((const unsigned short*)gnc)[p * 132 + d];
                accR[rt][r] = h2f((unsigned short)(rz & 0xffffu));
                accZ[rt][r] = h2f((unsigned short)(rz >> 16));
                gin[rt * 4 + r] = h2f(nn);
            }
            accH[rt] = (f32x4){bhn, bhn, bhn, bhn};
        }

        // MFMA: h-side only (48 MFMAs, 16 ds_read_b128 per wave)
        #pragma unroll
        for (int ks = 0; ks < 4; ++ks) {
            const int kb = ks * 4 + quad;
            #pragma unroll
            for (int rt = 0; rt < 4; ++rt) {
                const int p = rt * 16 + lcol;
                short8 ah = *(const short8*)(hr + p * DD + ((kb ^ lcol) * 8));
                accR[rt] = __builtin_amdgcn_mfma_f32_16x16x32_bf16(ah, Bh[0][ks], accR[rt], 0, 0, 0);
                accZ[rt] = __builtin_amdgcn_mfma_f32_16x16x32_bf16(ah, Bh[1][ks], accZ[rt], 0, 0, 0);
                accH[rt] = __builtin_amdgcn_mfma_f32_16x16x32_bf16(ah, Bh[2][ks], accH[rt], 0, 0, 0);
            }
        }

        if (t == LL - 1) __syncthreads();  // hs_f aliases hs0/hs1(+1KB gz0, dead)

        // GRU cell epilogue
        #pragma unroll
        for (int rt = 0; rt < 4; ++rt) {
            #pragma unroll
            for (int r = 0; r < 4; ++r) {
                const int idx = rt * 4 + r;
                const int p   = rt * 16 + quad * 4 + r;
                float rg = fast_sigmoid(accR[rt][r]);
                float zg = fast_sigmoid(accZ[rt][r]);
                float ng = fast_tanh(gin[idx] + rg * accH[rt][r]);  // accH = hn + b_hh_n
                float hnew = fmaf(zg, hreg[idx] - ng, ng);
                hreg[idx] = hnew;
                if (t < LL - 1) {
                    hw[p * DD + (((d >> 3) ^ (p & 15)) * 8) + (d & 7)] = f2bf(hnew);
                } else {
                    hs_f[p * HPAD + d] = hnew;   // fp32, aliases dead hs buffers
                }
            }
        }
        __syncthreads();   // hw complete; drains vmcnt -> t+1 gi tile landed
    }

    // attention logits + emit bf16 path embedding
    {
        int pi = tid >> 3, tt = tid & 7;
        float s0 = 0.f, s1 = 0.f, s2 = 0.f, s3 = 0.f;
        unsigned short pack[16];
        #pragma unroll
        for (int j = 0; j < 16; ++j) {
            int dd2 = tt * 16 + j;
            float hv = hs_f[pi * HPAD + dd2];
            pack[j] = f2bf(hv);
            float4 av = *(const float4*)(a + dd2 * 4);
            s0 += hv * av.x; s1 += hv * av.y; s2 += hv * av.z; s3 += hv * av.w;
        }
        uint4* dst = (uint4*)(emb + (size_t)(p0 + pi) * DD + tt * 16);
        dst[0] = *(uint4*)&pack[0];
        dst[1] = *(uint4*)&pack[8];
        float* rp = red_s + (pi * 8 + tt) * 4;
        rp[0] = s0; rp[1] = s1; rp[2] = s2; rp[3] = s3;
    }
    __syncthreads();
    if (tid < TM) {
        int pi = tid;
        int row = nodes_s[pi * LL + (LL - 1)];
        float4 e4;
        #pragma unroll
        for (int h = 0; h < HH; ++h) {
            float s = 0.f;
            #pragma unroll
            for (int tt = 0; tt < 8; ++tt) s += red_s[(pi * 8 + tt) * 4 + h];
            float lv = (s > 0.f) ? s : 0.2f * s;
            float e  = __expf(lv);
            ((float*)&e4)[h] = e;
            atomicAdd(&att_sum[row * HH + h], e);
        }
        *(float4*)(att_un_g + (size_t)(p0 + pi) * HH) = e4;
    }
    #undef STAGE_GI
}

// ---------------------------------------------------------------------------
// Pass B: per-node aggregation over its sorted paths. Atomic-free.
// ---------------------------------------------------------------------------
__global__ __launch_bounds__(256)
void agg_kernel(const unsigned short* __restrict__ emb,   // [P][128] bf16
                const float* __restrict__ att_un,         // [P][4]
                const float* __restrict__ att_sum,        // [N][4]
                const int* __restrict__ offs,
                const int* __restrict__ cnt,
                const int* __restrict__ sorted,
                float* __restrict__ out)                  // [N][512]
{
    int node = blockIdx.x * 2 + (threadIdx.x >> 7);
    int d    = threadIdx.x & 127;
    if (node >= NN) return;
    int start = offs[node];
    int len   = cnt[node];
    float a0 = 0.f, a1 = 0.f, a2 = 0.f, a3 = 0.f;
    for (int i = 0; i < len; ++i) {
        int p = sorted[start + i];
        float4 at = *(const float4*)(att_un + (size_t)p * 4);
        float ev = bf2f(emb[(size_t)p * DD + d]);
        a0 = fmaf(at.x, ev, a0);
        a1 = fmaf(at.y, ev, a1);
        a2 = fmaf(at.z, ev, a2);
        a3 = fmaf(at.w, ev, a3);
    }
    float4 s = *(const float4*)(att_sum + (size_t)node * 4);
    float* o = out + (size_t)node * 512 + d;
    o[0]   = (s.x > 0.f) ? a0 / s.x : 0.f;
    o[128] = (s.y > 0.f) ? a1 / s.y : 0.f;
    o[256] = (s.z > 0.f) ? a2 / s.z : 0.f;
    o[384] = (s.w > 0.f) ? a3 / s.w : 0.f;
}

extern "C" void kernel_launch(void* const* d_in, const int* in_sizes, int n_in,
                              void* d_out, int out_size, void* d_ws, size_t ws_size,
                              hipStream_t stream) {
    const float* x         = (const float*)d_in[0];
    const int*   path_list = (const int*)  d_in[1];
    const float* w_ih      = (const float*)d_in[2];
    const float* w_hh      = (const float*)d_in[3];
    const float* b_ih      = (const float*)d_in[4];
    const float* b_hh      = (const float*)d_in[5];
    const float* a         = (const float*)d_in[6];
    float* out = (float*)d_out;

    // workspace layout (all 16B-multiple sizes), total ~95 MB
    char* w = (char*)d_ws;
    float*          att_sum = (float*)w;                 w += 800000;       // N*4 f32
    int*            cnt     = (int*)w;                   w += 200000;       // N
    int*            offs    = (int*)w;                   w += 200000;       // N
    int*            cursor  = (int*)w;                   w += 200000;       // N
    int*            sorted  = (int*)w;                   w += 800000;       // P
    float*          att_un  = (float*)w;                 w += 3200000;      // P*4 f32
    unsigned int*   giRZ    = (unsigned int*)w;          w += 25600000;     // N*128 u32
    unsigned short* giN     = (unsigned short*)w;        w += 12800000;     // N*128 fp16
    unsigned short* whb     = (unsigned short*)w;        w += 98304;        // 384*128 bf16
    unsigned short* emb     = (unsigned short*)w;        w += 51200000;     // P*128 bf16

    hipMemsetAsync(att_sum, 0, 800000, stream);
    hipMemsetAsync(cnt, 0, 200000, stream);

    prep_w_kernel<<<(3 * DD * DD + 255) / 256, 256, 0, stream>>>(w_hh, whb);

    histo_kernel<<<(PP + 255) / 256, 256, 0, stream>>>(path_list, cnt);
    scan_kernel<<<1, 256, 0, stream>>>(cnt, offs, cursor);
    scatter_kernel<<<(PP + 255) / 256, 256, 0, stream>>>(path_list, cursor, sorted);

    gi_gemm_kernel<<<(NN + 63) / 64, 512, 0, stream>>>(x, w_ih, b_ih, b_hh, giRZ, giN);

    gru_att_kernel<<<PP / TM, NT, 0, stream>>>(giRZ, (const unsigned int*)giN,
                                               path_list, whb,
                                               b_hh, a, att_sum, emb, att_un);

    agg_kernel<<<(NN + 1) / 2, 256, 0, stream>>>(emb, att_un, att_sum,
                                                 offs, cnt, sorted, out);
}